// Round 3
// baseline (232.681 us; speedup 1.0000x reference)
//
#include <hip/hip_runtime.h>
#include <stdint.h>
#include <math.h>

// Problem constants (fixed by the reference)
#define NH   16
#define HDIM 64
#define SEQ  2048
#define DM   1024
#define NB   2
#define MTOK (NB * SEQ)   // 4096

typedef __bf16 bf16x8 __attribute__((ext_vector_type(8)));  // 4 VGPRs, MFMA A/B frag
typedef float  f32x4  __attribute__((ext_vector_type(4)));  // MFMA C/D frag

__device__ __forceinline__ unsigned short f2bf(float f) {
  union { float f; unsigned int u; } c; c.f = f;
  unsigned int u = c.u;
  return (unsigned short)((u + 0x7FFFu + ((u >> 16) & 1u)) >> 16);  // RNE
}

// async global->LDS, 16B per lane. LDS dest = wave-uniform base + lane*16 (m104/m108).
__device__ __forceinline__ void async_copy16(const void* g, void* l) {
  __builtin_amdgcn_global_load_lds((__attribute__((address_space(1))) void*)g,
                                   (__attribute__((address_space(3))) void*)l,
                                   16, 0, 0);
}

// ---------------------------------------------------------------- fused casts (1 launch)
// seg 0: x (n4=1M), segs 1-4: wq/wk/wv/wo (n4=256K each)
__global__ void cast_all(const float* __restrict__ x,  const float* __restrict__ wq,
                         const float* __restrict__ wk, const float* __restrict__ wv,
                         const float* __restrict__ wo,
                         unsigned short* __restrict__ xb,
                         unsigned short* __restrict__ wqkvb,
                         unsigned short* __restrict__ wob) {
  const int seg = blockIdx.y;
  const float* src;
  unsigned short* dst;
  int n4;
  if (seg == 0)      { src = x;  dst = xb;                  n4 = MTOK * DM / 4; }
  else if (seg == 1) { src = wq; dst = wqkvb;               n4 = DM * DM / 4; }
  else if (seg == 2) { src = wk; dst = wqkvb + DM * DM;     n4 = DM * DM / 4; }
  else if (seg == 3) { src = wv; dst = wqkvb + 2 * DM * DM; n4 = DM * DM / 4; }
  else               { src = wo; dst = wob;                 n4 = DM * DM / 4; }
  const int i = blockIdx.x * blockDim.x + threadIdx.x;
  if (i >= n4) return;
  float4 v = reinterpret_cast<const float4*>(src)[i];
  ushort4 o;
  o.x = f2bf(v.x); o.y = f2bf(v.y); o.z = f2bf(v.z); o.w = f2bf(v.w);
  reinterpret_cast<ushort4*>(dst)[i] = o;
}

// ---------------------------------------------------------------- GEMM (NT): C[m,n] = sum_k A[m,k]*B[n,k]
// m97 structure: 128x128 tile, BK=32, global_load_lds width-16 staging.
// MODE 0: Q (pre-scaled 1/8) / K -> [B,H,S,64] bf16; V -> transposed [B,H,64,S] bf16.
// MODE 1: fp32 out + bias, row-major.
template <int MODE>
__global__ __launch_bounds__(256, 2) void gemm_bt(
    const unsigned short* __restrict__ A,   // [M,K] bf16 bits
    const unsigned short* __restrict__ B,   // [N,K] bf16 bits
    unsigned short* __restrict__ qo, unsigned short* __restrict__ ko,
    unsigned short* __restrict__ vo,        // vo is V^T [B,H,64,SEQ]
    float* __restrict__ co, const float* __restrict__ bias,
    int M, int N, int K) {
  __shared__ __align__(16) unsigned short As[128 * 32];
  __shared__ __align__(16) unsigned short Bs[128 * 32];

  const int tid  = threadIdx.x;
  const int lane = tid & 63;
  const int wave = tid >> 6;
  const int l15  = lane & 15;
  const int quad = lane >> 4;
  const int wm   = (wave >> 1) * 64;
  const int wn   = (wave & 1) * 64;
  const int m0   = blockIdx.x * 128;
  const int n0   = blockIdx.y * 128;

  f32x4 acc[4][4];
#pragma unroll
  for (int a = 0; a < 4; ++a)
#pragma unroll
    for (int b = 0; b < 4; ++b) acc[a][b] = f32x4{0.f, 0.f, 0.f, 0.f};

  for (int k0 = 0; k0 < K; k0 += 32) {
    __syncthreads();
#pragma unroll
    for (int s = 0; s < 2; ++s) {             // 512 16B chunks / 256 threads
      const int c   = tid + s * 256;
      const int row = c >> 2;
      const int col = (c & 3) * 8;
      // LDS element offset for chunk c is c*8 == row*32+col; wave-uniform part:
      unsigned short* lA = As + ((size_t)wave * 64 + s * 256) * 8;
      unsigned short* lB = Bs + ((size_t)wave * 64 + s * 256) * 8;
      async_copy16(A + (size_t)(m0 + row) * K + k0 + col, lA);
      async_copy16(B + (size_t)(n0 + row) * K + k0 + col, lB);
    }
    __syncthreads();

    bf16x8 af[4], bfr[4];
#pragma unroll
    for (int t = 0; t < 4; ++t) {
      // A frag: m = lane&15, k = quad*8+j  (verified m89/m91 layout)
      af[t]  = *reinterpret_cast<const bf16x8*>(As + (wm + t * 16 + l15) * 32 + quad * 8);
      bfr[t] = *reinterpret_cast<const bf16x8*>(Bs + (wn + t * 16 + l15) * 32 + quad * 8);
    }
#pragma unroll
    for (int ti = 0; ti < 4; ++ti)
#pragma unroll
      for (int tj = 0; tj < 4; ++tj)
        acc[ti][tj] = __builtin_amdgcn_mfma_f32_16x16x32_bf16(af[ti], bfr[tj], acc[ti][tj], 0, 0, 0);
  }

  // C/D layout: col = lane&15, row = quad*4 + reg (verified m89/m91)
#pragma unroll
  for (int ti = 0; ti < 4; ++ti) {
#pragma unroll
    for (int tj = 0; tj < 4; ++tj) {
      const int mb = m0 + wm + ti * 16 + quad * 4;   // rows mb..mb+3
      const int n  = n0 + wn + tj * 16 + l15;
      if (MODE == 0) {
        const int which = n >> 10;          // 0:q 1:k 2:v
        const int n1 = n & 1023;
        const int h = n1 >> 6, d = n1 & 63;
        const int b = mb >> 11, s = mb & 2047;
        if (which == 0) {
          const size_t idx = ((size_t)(b * NH + h) * SEQ + s) * HDIM + d;
#pragma unroll
          for (int r = 0; r < 4; ++r) qo[idx + (size_t)r * HDIM] = f2bf(acc[ti][tj][r] * 0.125f);
        } else if (which == 1) {
          const size_t idx = ((size_t)(b * NH + h) * SEQ + s) * HDIM + d;
#pragma unroll
          for (int r = 0; r < 4; ++r) ko[idx + (size_t)r * HDIM] = f2bf(acc[ti][tj][r]);
        } else {
          // V^T: [b,h,d,s] — 4 consecutive s per lane -> packed 8B store
          const size_t idx = ((size_t)(b * NH + h) * HDIM + d) * SEQ + s;
          ushort4 pk;
          pk.x = f2bf(acc[ti][tj][0]); pk.y = f2bf(acc[ti][tj][1]);
          pk.z = f2bf(acc[ti][tj][2]); pk.w = f2bf(acc[ti][tj][3]);
          *reinterpret_cast<ushort4*>(vo + idx) = pk;
        }
      } else {
#pragma unroll
        for (int r = 0; r < 4; ++r)
          co[(size_t)(mb + r) * N + n] = acc[ti][tj][r] + bias[n];
      }
    }
  }
}

// ---------------------------------------------------------------- MFMA flash attention, Q-tile 128
// Block = 4 waves. Each wave owns TWO 16-row q-strips: q = q0 + strip*64 + wave*16 + l15.
// K staged in 64-key tiles; S^T = K·Q^T (lane owns one q-col -> scalar softmax state);
// shared Ks/Vt fragment reads across both strips; P -> LDS bf16 -> PV with V^T.
#define KS_STRIDE 80   // 64 + 16 pad: bank-balanced frag reads, 16B-aligned rows
#define PT_STRIDE 80

__global__ __launch_bounds__(256, 3) void flash_attn_mfma(
    const unsigned short* __restrict__ Qb,   // [bh][s][64], pre-scaled by 1/8
    const unsigned short* __restrict__ Kb,   // [bh][s][64]
    const unsigned short* __restrict__ Vtg,  // [bh][d][2048]  (V^T)
    unsigned short* __restrict__ ctx) {      // [b][s][1024] bf16
  __shared__ __align__(16) unsigned short Ks[64 * KS_STRIDE];
  __shared__ __align__(16) unsigned short Vt[64 * KS_STRIDE];
  __shared__ __align__(16) unsigned short Pt[4][2][16 * PT_STRIDE];

  const int tid  = threadIdx.x;
  const int qt   = gridDim.x - 1 - blockIdx.x;  // heavy (long-loop) blocks first
  const int bh   = blockIdx.y;
  const int q0   = qt * 128;
  const int lane = tid & 63;
  const int wave = tid >> 6;
  const int l15  = lane & 15;
  const int quad = lane >> 4;

  const size_t baseQK = (size_t)bh * SEQ * HDIM;
  const size_t baseV  = (size_t)bh * HDIM * SEQ;

  // Q fragments (B-operand of S^T) for both strips
  bf16x8 qf[2][2];
#pragma unroll
  for (int sp = 0; sp < 2; ++sp) {
    const unsigned short* qp =
        Qb + baseQK + (size_t)(q0 + sp * 64 + wave * 16 + l15) * HDIM + quad * 8;
    qf[sp][0] = *reinterpret_cast<const bf16x8*>(qp);
    qf[sp][1] = *reinterpret_cast<const bf16x8*>(qp + 32);
  }

  float m_s[2] = {-INFINITY, -INFINITY};
  float l_s[2] = {0.f, 0.f};
  f32x4 o[2][4];   // o[sp][td][r] = O[q=quad*4+r][d=td*16+l15] of strip sp
#pragma unroll
  for (int sp = 0; sp < 2; ++sp)
#pragma unroll
    for (int td = 0; td < 4; ++td) o[sp][td] = f32x4{0.f, 0.f, 0.f, 0.f};

  const int ktmax = 2 * qt + 1;
  for (int kt = 0; kt <= ktmax; ++kt) {
    __syncthreads();   // previous iteration done reading Ks/Vt
    {
      const int row = tid >> 3;
      const int col = (tid & 7) * 8;
#pragma unroll
      for (int s = 0; s < 2; ++s) {
        const int r2 = row + s * 32;
        const uint4 kv = *reinterpret_cast<const uint4*>(Kb + baseQK + (size_t)(kt * 64 + r2) * HDIM + col);
        const uint4 vv = *reinterpret_cast<const uint4*>(Vtg + baseV + (size_t)r2 * SEQ + kt * 64 + col);
        *reinterpret_cast<uint4*>(&Ks[r2 * KS_STRIDE + col]) = kv;
        *reinterpret_cast<uint4*>(&Vt[r2 * KS_STRIDE + col]) = vv;
      }
    }
    __syncthreads();

    // rel (in 16-key units): subtile t full if t<rel, diagonal if t==rel, masked if t>rel
    const int rel0 = ((q0 + wave * 16) >> 4) - kt * 4;  // strip0
    const int rel1 = rel0 + 4;                           // strip1 (always >= 0 here)

    // S^T: st[sp][t][r] = S[key = kt*64 + t*16 + quad*4 + r][q = l15 of strip sp]
    f32x4 st[2][4];
#pragma unroll
    for (int sp = 0; sp < 2; ++sp)
#pragma unroll
      for (int t = 0; t < 4; ++t)
        st[sp][t] = f32x4{-INFINITY, -INFINITY, -INFINITY, -INFINITY};

#pragma unroll
    for (int t = 0; t < 4; ++t) {
      if (t <= rel1) {   // strip1 needs it (superset of strip0's need)
        const bf16x8 kf0 = *reinterpret_cast<const bf16x8*>(&Ks[(t * 16 + l15) * KS_STRIDE + quad * 8]);
        const bf16x8 kf1 = *reinterpret_cast<const bf16x8*>(&Ks[(t * 16 + l15) * KS_STRIDE + 32 + quad * 8]);
        if (t <= rel0) {
          f32x4 c = f32x4{0.f, 0.f, 0.f, 0.f};
          c = __builtin_amdgcn_mfma_f32_16x16x32_bf16(kf0, qf[0][0], c, 0, 0, 0);
          c = __builtin_amdgcn_mfma_f32_16x16x32_bf16(kf1, qf[0][1], c, 0, 0, 0);
          if (t == rel0) {
#pragma unroll
            for (int r = 0; r < 4; ++r)
              if (quad * 4 + r > l15) c[r] = -INFINITY;
          }
          st[0][t] = c;
        }
        {
          f32x4 c = f32x4{0.f, 0.f, 0.f, 0.f};
          c = __builtin_amdgcn_mfma_f32_16x16x32_bf16(kf0, qf[1][0], c, 0, 0, 0);
          c = __builtin_amdgcn_mfma_f32_16x16x32_bf16(kf1, qf[1][1], c, 0, 0, 0);
          if (t == rel1) {
#pragma unroll
            for (int r = 0; r < 4; ++r)
              if (quad * 4 + r > l15) c[r] = -INFINITY;
          }
          st[1][t] = c;
        }
      }
    }

    // online softmax per strip (wave-uniform skip when strip fully masked)
#pragma unroll
    for (int sp = 0; sp < 2; ++sp) {
      const int rel = sp ? rel1 : rel0;
      if (rel < 0) continue;
      float mx = -INFINITY;
#pragma unroll
      for (int t = 0; t < 4; ++t)
#pragma unroll
        for (int r = 0; r < 4; ++r) mx = fmaxf(mx, st[sp][t][r]);
      mx = fmaxf(mx, __shfl_xor(mx, 16, 64));
      mx = fmaxf(mx, __shfl_xor(mx, 32, 64));
      const float mnew  = fmaxf(m_s[sp], mx);
      const float alpha = __expf(m_s[sp] - mnew);
      m_s[sp] = mnew;

      float rs = 0.f;
#pragma unroll
      for (int t = 0; t < 4; ++t) {
        ushort4 pk;
        const float p0 = __expf(st[sp][t][0] - mnew);
        const float p1 = __expf(st[sp][t][1] - mnew);
        const float p2 = __expf(st[sp][t][2] - mnew);
        const float p3 = __expf(st[sp][t][3] - mnew);
        rs += (p0 + p1) + (p2 + p3);
        pk.x = f2bf(p0); pk.y = f2bf(p1); pk.z = f2bf(p2); pk.w = f2bf(p3);
        *reinterpret_cast<ushort4*>(&Pt[wave][sp][l15 * PT_STRIDE + t * 16 + quad * 4]) = pk;
      }
      rs += __shfl_xor(rs, 16, 64);
      rs += __shfl_xor(rs, 32, 64);
      l_s[sp] = l_s[sp] * alpha + rs;

#pragma unroll
      for (int r = 0; r < 4; ++r) {
        const float ar = __shfl(alpha, quad * 4 + r, 64);
#pragma unroll
        for (int td = 0; td < 4; ++td) o[sp][td][r] *= ar;
      }
    }

    // O += P·V — Vt fragment reads shared across strips
    const bool s0 = (rel0 >= 0);
#pragma unroll
    for (int s = 0; s < 2; ++s) {
      bf16x8 pf0, pf1;
      if (s0) pf0 = *reinterpret_cast<const bf16x8*>(&Pt[wave][0][l15 * PT_STRIDE + s * 32 + quad * 8]);
      pf1 = *reinterpret_cast<const bf16x8*>(&Pt[wave][1][l15 * PT_STRIDE + s * 32 + quad * 8]);
#pragma unroll
      for (int td = 0; td < 4; ++td) {
        const bf16x8 vf = *reinterpret_cast<const bf16x8*>(&Vt[(td * 16 + l15) * KS_STRIDE + s * 32 + quad * 8]);
        if (s0) o[0][td] = __builtin_amdgcn_mfma_f32_16x16x32_bf16(pf0, vf, o[0][td], 0, 0, 0);
        o[1][td] = __builtin_amdgcn_mfma_f32_16x16x32_bf16(pf1, vf, o[1][td], 0, 0, 0);
      }
    }
  }

  // epilogue: normalize and write ctx[b][s][h*64+d] bf16
  const int b = bh >> 4, h = bh & 15;
#pragma unroll
  for (int sp = 0; sp < 2; ++sp) {
    const float linv = 1.f / l_s[sp];   // for q = l15
#pragma unroll
    for (int r = 0; r < 4; ++r) {
      const float lr = __shfl(linv, quad * 4 + r, 64);
      const int srow = q0 + sp * 64 + wave * 16 + quad * 4 + r;
      const size_t ob = (size_t)(b * SEQ + srow) * DM + h * HDIM + l15;
#pragma unroll
      for (int td = 0; td < 4; ++td)
        ctx[ob + td * 16] = f2bf(o[sp][td][r] * lr);
    }
  }
}

// ---------------------------------------------------------------- launch
extern "C" void kernel_launch(void* const* d_in, const int* in_sizes, int n_in,
                              void* d_out, int out_size, void* d_ws, size_t ws_size,
                              hipStream_t stream) {
  const float* x  = (const float*)d_in[0];
  const float* wq = (const float*)d_in[1];
  const float* wk = (const float*)d_in[2];
  const float* wv = (const float*)d_in[3];
  const float* wo = (const float*)d_in[4];
  const float* bo = (const float*)d_in[5];
  float* out = (float*)d_out;

  // ws layout (48 MB total)
  char* ws = (char*)d_ws;
  unsigned short* xb    = (unsigned short*)(ws);                    // [4096,1024]    8 MB
  unsigned short* wqkvb = (unsigned short*)(ws + (8ull  << 20));    // [3072,1024]    6 MB
  unsigned short* wob   = (unsigned short*)(ws + (14ull << 20));    // [1024,1024]    2 MB
  unsigned short* Qb    = (unsigned short*)(ws + (16ull << 20));    // [32,2048,64]   8 MB (pre-scaled)
  unsigned short* Kb    = (unsigned short*)(ws + (24ull << 20));    // [32,2048,64]   8 MB
  unsigned short* Vtg   = (unsigned short*)(ws + (32ull << 20));    // [32,64,2048]   8 MB (V^T)
  unsigned short* ctxb  = (unsigned short*)(ws + (40ull << 20));    // [4096,1024]    8 MB

  dim3 gc(4096, 5);
  cast_all<<<gc, 256, 0, stream>>>(x, wq, wk, wv, wo, xb, wqkvb, wob);

  dim3 g1(MTOK / 128, (3 * DM) / 128);   // 32 x 24
  gemm_bt<0><<<g1, 256, 0, stream>>>(xb, wqkvb, Qb, Kb, Vtg, nullptr, nullptr,
                                     MTOK, 3 * DM, DM);

  dim3 g2(SEQ / 128, NB * NH);           // 16 x 32
  flash_attn_mfma<<<g2, 256, 0, stream>>>(Qb, Kb, Vtg, ctxb);

  dim3 g3(MTOK / 128, DM / 128);         // 32 x 8
  gemm_bt<1><<<g3, 256, 0, stream>>>(ctxb, wob, nullptr, nullptr, nullptr, out, bo,
                                     MTOK, DM, DM);
}